// Round 8
// baseline (200.592 us; speedup 1.0000x reference)
//
#include <hip/hip_runtime.h>

typedef __attribute__((ext_vector_type(4))) float  f32x4;
typedef __attribute__((ext_vector_type(4))) short  s16x4;
typedef __attribute__((ext_vector_type(8))) short  s16x8;
typedef __bf16 bf16x8 __attribute__((ext_vector_type(8)));

#define NBATCH 16
#define SEQ    4096
#define KIN    256
#define HY     64
#define HOUT   512
#define NROWS  (NBATCH*SEQ)   /* 65536 */
#define LC     32
#define NC     (SEQ/LC)       /* 128 */

static __device__ __forceinline__ short f2bf(float f) {
  unsigned u = __float_as_uint(f);
  u = u + 0x7FFF + ((u >> 16) & 1);          // RNE
  return (short)(u >> 16);
}
static __device__ __forceinline__ float bf2f(short h) {
  return __uint_as_float(((unsigned)(unsigned short)h) << 16);
}
static __device__ __forceinline__ f32x4 mfma16(bf16x8 a, bf16x8 b, f32x4 c) {
  return __builtin_amdgcn_mfma_f32_16x16x32_bf16(a, b, c, 0, 0, 0);
}
static __device__ __forceinline__ bf16x8 ldfrag(const short* p) {
  return *reinterpret_cast<const bf16x8*>(p);
}
static __device__ __forceinline__ float fsigmoid(float z) {
  return 1.f / (1.f + __expf(-z));
}

// ---------------- weight prep (all plain bf16)
__global__ void prep_w(const float* __restrict__ lin0W, const float* __restrict__ sig0W,
                       const float* __restrict__ fchW,  const float* __restrict__ fc2W,
                       short* __restrict__ W1h, short* __restrict__ W2h,
                       short* __restrict__ Fh,  short* __restrict__ F2h) {
  int i = blockIdx.x * 256 + threadIdx.x;
  if (i < 16384) {
    W1h[i] = f2bf(lin0W[i]);
    W2h[i] = f2bf(sig0W[i]);
  } else if (i < 16384 + 32768) {
    Fh[i - 16384] = f2bf(fchW[i - 16384]);
  } else if (i < 16384 + 32768 + 131072) {
    F2h[i - 49152] = f2bf(fc2W[i - 49152]);
  }
}

// ---------------- galpha: per 64-row block:
//   g     = relu( (x@lin0^T+b) * sigmoid(x@sig0^T+b) )   -> Gh (bf16)
//   alpha = sigmoid( x@fc2^T + b )                        -> AB (bf16)
// SWAPPED MFMA operands: D row (=(l>>4)*4+reg) indexes OUTPUT COLS -> s16x4 8B packed stores.
__global__ __launch_bounds__(256) void galpha(
    const float* __restrict__ x,
    const short* __restrict__ W1h, const short* __restrict__ W2h,
    const short* __restrict__ F2h,
    const float* __restrict__ lin0b, const float* __restrict__ sig0b,
    const float* __restrict__ fc2b,
    short* __restrict__ Gh, short* __restrict__ AB) {
  __shared__ short Ah[64 * 256];       // 32KB, XOR-swizzled rows
  int tid = threadIdx.x;
  int row0 = blockIdx.x * 64;
  #pragma unroll
  for (int i = 0; i < 16; ++i) {
    int f4 = tid + i * 256;
    int r = f4 >> 6, k = (f4 & 63) << 2;
    f32x4 v = *reinterpret_cast<const f32x4*>(x + (size_t)(row0 + r) * KIN + k);
    s16x4 hh;
    #pragma unroll
    for (int j = 0; j < 4; ++j) hh[j] = f2bf(v[j]);
    *reinterpret_cast<s16x4*>(&Ah[(r * 256 + k) ^ ((r & 7) << 3)]) = hh;
  }
  __syncthreads();
  int w = tid >> 6, l = tid & 63, lr = l & 15, lg = l >> 4;
  // ---- phase 1: g (wave owns g-cols [16w,16w+16); D-col = x-row)
  {
    int c = w * 16 + lr;               // A-operand row = g col
    f32x4 a1[4], a2[4];
    #pragma unroll
    for (int rt = 0; rt < 4; ++rt) { a1[rt] = (f32x4)0.f; a2[rt] = (f32x4)0.f; }
    #pragma unroll
    for (int ks = 0; ks < 8; ++ks) {
      int kk = ks * 32 + lg * 8;
      bf16x8 b1 = ldfrag(W1h + c * 256 + kk);
      bf16x8 b2 = ldfrag(W2h + c * 256 + kk);
      #pragma unroll
      for (int rt = 0; rt < 4; ++rt) {
        int r = rt * 16 + lr;
        bf16x8 a = ldfrag(&Ah[(r * 256 + kk) ^ ((r & 7) << 3)]);
        a1[rt] = mfma16(b1, a, a1[rt]);     // swapped
        a2[rt] = mfma16(b2, a, a2[rt]);
      }
    }
    f32x4 blv = *reinterpret_cast<const f32x4*>(lin0b + w * 16 + lg * 4);
    f32x4 bsv = *reinterpret_cast<const f32x4*>(sig0b + w * 16 + lg * 4);
    #pragma unroll
    for (int rt = 0; rt < 4; ++rt) {
      int xrow = row0 + rt * 16 + lr;       // D col = x row
      s16x4 gg;
      #pragma unroll
      for (int j = 0; j < 4; ++j) {
        float g = (a1[rt][j] + blv[j]) * fsigmoid(a2[rt][j] + bsv[j]);
        gg[j] = f2bf(g > 0.f ? g : 0.f);
      }
      *reinterpret_cast<s16x4*>(Gh + (size_t)xrow * HY + w * 16 + lg * 4) = gg;
    }
  }
  // ---- phase 2: alpha (wave owns cols [128w,128w+128), 2 passes x 64 cols)
  #pragma unroll
  for (int p = 0; p < 2; ++p) {
    f32x4 acc[4][4];                        // [colTile][xrowTile]
    #pragma unroll
    for (int ci = 0; ci < 4; ++ci)
      #pragma unroll
      for (int rt = 0; rt < 4; ++rt) acc[ci][rt] = (f32x4)0.f;
    #pragma unroll
    for (int ks = 0; ks < 8; ++ks) {
      int kk = ks * 32 + lg * 8;
      bf16x8 Wf[4], Xf[4];
      #pragma unroll
      for (int ci = 0; ci < 4; ++ci) {
        int col = w * 128 + p * 64 + ci * 16 + lr;
        Wf[ci] = ldfrag(F2h + (size_t)col * KIN + kk);
      }
      #pragma unroll
      for (int rt = 0; rt < 4; ++rt) {
        int r = rt * 16 + lr;
        Xf[rt] = ldfrag(&Ah[(r * 256 + kk) ^ ((r & 7) << 3)]);
      }
      #pragma unroll
      for (int ci = 0; ci < 4; ++ci)
        #pragma unroll
        for (int rt = 0; rt < 4; ++rt)
          acc[ci][rt] = mfma16(Wf[ci], Xf[rt], acc[ci][rt]);
    }
    #pragma unroll
    for (int ci = 0; ci < 4; ++ci) {
      int colb = w * 128 + p * 64 + ci * 16 + lg * 4;
      f32x4 b2v = *reinterpret_cast<const f32x4*>(fc2b + colb);
      #pragma unroll
      for (int rt = 0; rt < 4; ++rt) {
        int xrow = row0 + rt * 16 + lr;
        s16x4 av;
        #pragma unroll
        for (int j = 0; j < 4; ++j) av[j] = f2bf(fsigmoid(acc[ci][rt][j] + b2v[j]));
        *reinterpret_cast<s16x4*>(AB + (size_t)xrow * HOUT + colb) = av;
      }
    }
  }
}

// ---------------- bscan: per chunk (32 rows x 512 cols): b = (g@fch^T + bc) * alpha (bf16,
// overwrites alpha in AB in place); wave0 builds chunk max-plus operator (C,S). Swapped MFMA.
__global__ __launch_bounds__(256) void bscan(
    const short* __restrict__ Gh, const short* __restrict__ Fh,
    const float* __restrict__ fchb,
    short* __restrict__ AB,
    float* __restrict__ Cc, float* __restrict__ Sc) {
  __shared__ __align__(16) char smem[32768];
  short* AG = (short*)smem;            // 32x64 shorts, swizzled (K-loop phase)
  short* bL = (short*)smem;            // 32x512 shorts, swizzled (epilogue phase)
  int tid = threadIdx.x;
  int bc = blockIdx.x;
  int row0 = bc * LC;
  {
    int r = tid >> 3, k8 = tid & 7;
    s16x8 v = *reinterpret_cast<const s16x8*>(Gh + (size_t)(row0 + r) * HY + k8 * 8);
    *reinterpret_cast<s16x8*>(&AG[(r * 64 + k8 * 8) ^ ((r & 7) << 3)]) = v;
  }
  __syncthreads();
  int w = tid >> 6, l = tid & 63, lr = l & 15, lg = l >> 4;
  f32x4 acc[8][2];                      // [colTile][xrowTile]
  #pragma unroll
  for (int ci = 0; ci < 8; ++ci)
    #pragma unroll
    for (int rt = 0; rt < 2; ++rt) acc[ci][rt] = (f32x4)0.f;
  #pragma unroll
  for (int ks = 0; ks < 2; ++ks) {
    int kk = ks * 32 + lg * 8;
    bf16x8 Wf[8], Af[2];
    #pragma unroll
    for (int ci = 0; ci < 8; ++ci) {
      int col = w * 128 + ci * 16 + lr;
      Wf[ci] = ldfrag(Fh + (size_t)col * HY + kk);
    }
    #pragma unroll
    for (int rt = 0; rt < 2; ++rt) {
      int r = rt * 16 + lr;
      Af[rt] = ldfrag(&AG[(r * 64 + kk) ^ ((r & 7) << 3)]);
    }
    #pragma unroll
    for (int ci = 0; ci < 8; ++ci)
      #pragma unroll
      for (int rt = 0; rt < 2; ++rt)
        acc[ci][rt] = mfma16(Wf[ci], Af[rt], acc[ci][rt]);
  }
  // gate with alpha (8B loads; read-before-overwrite, same block's rows only)
  float bvals[8][2][4];
  #pragma unroll
  for (int ci = 0; ci < 8; ++ci) {
    int colb = w * 128 + ci * 16 + lg * 4;
    f32x4 bcv = *reinterpret_cast<const f32x4*>(fchb + colb);
    #pragma unroll
    for (int rt = 0; rt < 2; ++rt) {
      int xrow = row0 + rt * 16 + lr;
      s16x4 av = *reinterpret_cast<const s16x4*>(AB + (size_t)xrow * HOUT + colb);
      #pragma unroll
      for (int j = 0; j < 4; ++j)
        bvals[ci][rt][j] = (acc[ci][rt][j] + bcv[j]) * bf2f(av[j]);
    }
  }
  __syncthreads();                      // AG dead; smem becomes bL
  #pragma unroll
  for (int ci = 0; ci < 8; ++ci) {
    int colb = w * 128 + ci * 16 + lg * 4;
    #pragma unroll
    for (int rt = 0; rt < 2; ++rt) {
      int tl = rt * 16 + lr;            // local x row
      s16x4 bb;
      #pragma unroll
      for (int j = 0; j < 4; ++j) bb[j] = f2bf(bvals[ci][rt][j]);
      *reinterpret_cast<s16x4*>(&bL[(tl * HOUT + colb) ^ ((tl & 15) << 3)]) = bb;
    }
  }
  __syncthreads();
  // coalesced in-place overwrite of AB rows with bf16 b
  #pragma unroll
  for (int i = 0; i < 8; ++i) {
    int slot = i * 256 + tid;
    int t = slot >> 6, s8 = slot & 63;
    s16x8 v = *reinterpret_cast<const s16x8*>(&bL[(t * HOUT + s8 * 8) ^ ((t & 15) << 3)]);
    *reinterpret_cast<s16x8*>(AB + (size_t)(row0 + t) * HOUT + s8 * 8) = v;
  }
  // chunk operator build (wave 0)
  if (w == 0) {
    float C[8], S[8];
    {
      s16x8 v = *reinterpret_cast<const s16x8*>(&bL[l * 8]);
      #pragma unroll
      for (int i = 0; i < 8; ++i) { S[i] = bf2f(v[i]); C[i] = 0.f; }
    }
    for (int t = 1; t < LC; ++t) {
      s16x8 v = *reinterpret_cast<const s16x8*>(&bL[(t * HOUT + l * 8) ^ ((t & 15) << 3)]);
      float bb[8];
      #pragma unroll
      for (int i = 0; i < 8; ++i) bb[i] = bf2f(v[i]);
      float pC = __shfl(C[7], (l + 63) & 63);
      float pS = __shfl(S[7], (l + 63) & 63);
      #pragma unroll
      for (int i = 7; i >= 1; --i) { C[i] = fmaxf(0.f, bb[i] + C[i - 1]); S[i] = bb[i] + S[i - 1]; }
      C[0] = fmaxf(0.f, bb[0] + pC);
      S[0] = bb[0] + pS;
    }
    float* cp = Cc + (size_t)bc * HOUT + l * 8;
    float* sp = Sc + (size_t)bc * HOUT + l * 8;
    #pragma unroll
    for (int i = 0; i < 8; ++i) { cp[i] = C[i]; sp[i] = S[i]; }
  }
}

// ---------------- combine: sequential over chunks per batch; emits h_in per chunk + last.
__global__ __launch_bounds__(64) void scan_combine(const float* __restrict__ hidden,
                                                   const float* __restrict__ Cc, const float* __restrict__ Sc,
                                                   float* __restrict__ hIn, float* __restrict__ lastOut) {
  int batch = blockIdx.x;
  int l = threadIdx.x;
  float h[8];
  const float* hp = hidden + batch * HOUT + l * 8;
  #pragma unroll
  for (int i = 0; i < 8; ++i) h[i] = hp[i];
  size_t base0 = ((size_t)batch * NC) * HOUT + l * 8;
  f32x4 c0 = *reinterpret_cast<const f32x4*>(Cc + base0);
  f32x4 c1 = *reinterpret_cast<const f32x4*>(Cc + base0 + 4);
  f32x4 s0 = *reinterpret_cast<const f32x4*>(Sc + base0);
  f32x4 s1 = *reinterpret_cast<const f32x4*>(Sc + base0 + 4);
  for (int c = 0; c < NC; ++c) {
    size_t base = base0 + (size_t)c * HOUT;
    f32x4 nc0, nc1, ns0, ns1;
    if (c + 1 < NC) {
      size_t nb = base + HOUT;
      nc0 = *reinterpret_cast<const f32x4*>(Cc + nb);
      nc1 = *reinterpret_cast<const f32x4*>(Cc + nb + 4);
      ns0 = *reinterpret_cast<const f32x4*>(Sc + nb);
      ns1 = *reinterpret_cast<const f32x4*>(Sc + nb + 4);
    }
    #pragma unroll
    for (int i = 0; i < 8; ++i) hIn[base + i] = h[i];
    float hs[8];
    #pragma unroll
    for (int i = 0; i < 8; ++i) hs[i] = __shfl(h[i], (l + 64 - (LC / 8)) & 63);
    #pragma unroll
    for (int i = 0; i < 4; ++i) {
      h[i]     = fmaxf(c0[i], s0[i] + hs[i]);
      h[4 + i] = fmaxf(c1[i], s1[i] + hs[4 + i]);
    }
    c0 = nc0; c1 = nc1; s0 = ns0; s1 = ns1;
  }
  float* lp = lastOut + batch * HOUT + l * 8;
  #pragma unroll
  for (int i = 0; i < 8; ++i) lp[i] = h[i];
}

// ---------------- pass B: replay recurrence from bf16 b (in AB), prefetched; fp32 h -> d_out.
__global__ __launch_bounds__(64) void scan_passB(const short* __restrict__ bws,
                                                 const float* __restrict__ hIn,
                                                 float* __restrict__ hout) {
  int bc = blockIdx.x;
  int l = threadIdx.x;
  int row0 = bc * LC;
  const float* hp = hIn + (size_t)bc * HOUT + l * 8;
  float h[8];
  #pragma unroll
  for (int i = 0; i < 8; ++i) h[i] = hp[i];
  s16x8 vc = *reinterpret_cast<const s16x8*>(bws + (size_t)row0 * HOUT + l * 8);
  for (int t = 0; t < LC; ++t) {
    s16x8 vn;
    if (t + 1 < LC)
      vn = *reinterpret_cast<const s16x8*>(bws + (size_t)(row0 + t + 1) * HOUT + l * 8);
    float bb[8];
    #pragma unroll
    for (int i = 0; i < 8; ++i) bb[i] = bf2f(vc[i]);
    float ph = __shfl(h[7], (l + 63) & 63);
    #pragma unroll
    for (int i = 7; i >= 1; --i) h[i] = fmaxf(0.f, bb[i] + h[i - 1]);
    h[0] = fmaxf(0.f, bb[0] + ph);
    f32x4 o0, o1;
    #pragma unroll
    for (int i = 0; i < 4; ++i) { o0[i] = h[i]; o1[i] = h[4 + i]; }
    float* bt = hout + (size_t)(row0 + t) * HOUT + l * 8;
    *reinterpret_cast<f32x4*>(bt) = o0;
    *reinterpret_cast<f32x4*>(bt + 4) = o1;
    vc = vn;
  }
}

extern "C" void kernel_launch(void* const* d_in, const int* in_sizes, int n_in,
                              void* d_out, int out_size, void* d_ws, size_t ws_size,
                              hipStream_t stream) {
  (void)in_sizes; (void)n_in; (void)out_size; (void)ws_size;
  const float* x      = (const float*)d_in[0];
  const float* hidden = (const float*)d_in[1];
  const float* lin0W  = (const float*)d_in[2];
  const float* lin0b  = (const float*)d_in[3];
  const float* sig0W  = (const float*)d_in[4];
  const float* sig0b  = (const float*)d_in[5];
  const float* fchW   = (const float*)d_in[6];
  const float* fchb   = (const float*)d_in[7];
  const float* fc2W   = (const float*)d_in[8];
  const float* fc2b   = (const float*)d_in[9];
  float* outO  = (float*)d_out;
  float* lastO = outO + (size_t)NROWS * HOUT;

  char* wsb = (char*)d_ws;
  size_t off = 0;
  auto alloc = [&](size_t bytes) { char* p = wsb + off; off += (bytes + 255) & ~(size_t)255; return p; };
  float* Cc  = (float*)alloc((size_t)NBATCH * NC * HOUT * 4);
  float* Sc  = (float*)alloc((size_t)NBATCH * NC * HOUT * 4);
  float* hIn = (float*)alloc((size_t)NBATCH * NC * HOUT * 4);
  short* W1h = (short*)alloc(HY * KIN * 2);
  short* W2h = (short*)alloc(HY * KIN * 2);
  short* Fh  = (short*)alloc(HOUT * HY * 2);
  short* F2h = (short*)alloc(HOUT * KIN * 2);
  short* Gh  = (short*)alloc((size_t)NROWS * HY * 2);
  short* AB  = (short*)alloc((size_t)NROWS * HOUT * 2);   // alpha, then b (bf16), in place

  prep_w<<<704, 256, 0, stream>>>(lin0W, sig0W, fchW, fc2W, W1h, W2h, Fh, F2h);
  galpha<<<NROWS / 64, 256, 0, stream>>>(x, W1h, W2h, F2h, lin0b, sig0b, fc2b, Gh, AB);
  bscan<<<NBATCH * NC, 256, 0, stream>>>(Gh, Fh, fchb, AB, Cc, Sc);
  scan_combine<<<NBATCH, 64, 0, stream>>>(hidden, Cc, Sc, hIn, lastO);
  scan_passB<<<NBATCH * NC, 64, 0, stream>>>(AB, hIn, outO);
}